// Round 3
// baseline (1299.928 us; speedup 1.0000x reference)
//
#include <hip/hip_runtime.h>
#include <hip/hip_bf16.h>

#define NN   10000
#define NE   320000
#define NF   128
#define SIXF 768
#define K21  21

typedef unsigned short u16;
typedef unsigned int   u32;

__device__ __forceinline__ float bf2f_lo(u32 pk) { return __uint_as_float(pk << 16); }
__device__ __forceinline__ float bf2f_hi(u32 pk) { return __uint_as_float(pk & 0xffff0000u); }
__device__ __forceinline__ u16 f2bf(float f) {
    u32 x = __float_as_uint(f);
    return (u16)((x + 0x7fffu + ((x >> 16) & 1u)) >> 16);
}

// ---------------- K0: out = [s ; v] ----------------
__global__ __launch_bounds__(256) void init_out_kernel(
    const float4* __restrict__ s4, const float4* __restrict__ v4, float4* __restrict__ out4)
{
    int i = blockIdx.x * 256 + threadIdx.x;   // 1,280,000 float4 total, exact
    if (i < NN * NF / 4) out4[i] = s4[i];
    else                 out4[i] = v4[i - NN * NF / 4];
}

// ---------------- K1: phi = silu(s@W1+b1)@W2+b2 -> bf16 ----------------
__global__ __launch_bounds__(256) void phi_kernel(
    const float* __restrict__ s, const float* __restrict__ W1, const float* __restrict__ b1,
    const float* __restrict__ W2, const float* __restrict__ b2, u16* __restrict__ phiw)
{
    __shared__ float sh[32][NF];
    __shared__ float hh[32][NF];
    const int t = threadIdx.x;
    const int row0 = blockIdx.x * 32;

    for (int i = t; i < 32 * NF / 4; i += 256) {
        int r = i >> 5, c4 = i & 31;
        float4 val = make_float4(0.f, 0.f, 0.f, 0.f);
        if (row0 + r < NN) val = *reinterpret_cast<const float4*>(&s[(size_t)(row0 + r) * NF + c4 * 4]);
        *reinterpret_cast<float4*>(&sh[r][c4 * 4]) = val;
    }
    __syncthreads();
    {
        const int c = t & 127;
        const int half = t >> 7;
        float hacc[16];
        #pragma unroll
        for (int i = 0; i < 16; ++i) hacc[i] = 0.f;
        for (int k4 = 0; k4 < 32; ++k4) {
            float w0 = W1[(k4 * 4 + 0) * NF + c];
            float w1 = W1[(k4 * 4 + 1) * NF + c];
            float w2 = W1[(k4 * 4 + 2) * NF + c];
            float w3 = W1[(k4 * 4 + 3) * NF + c];
            #pragma unroll
            for (int rr = 0; rr < 16; ++rr) {
                float4 sv = *reinterpret_cast<const float4*>(&sh[half * 16 + rr][k4 * 4]);
                hacc[rr] = fmaf(sv.x, w0, hacc[rr]);
                hacc[rr] = fmaf(sv.y, w1, hacc[rr]);
                hacc[rr] = fmaf(sv.z, w2, hacc[rr]);
                hacc[rr] = fmaf(sv.w, w3, hacc[rr]);
            }
        }
        float b1c = b1[c];
        #pragma unroll
        for (int rr = 0; rr < 16; ++rr) {
            float x = hacc[rr] + b1c;
            float sg = 1.0f / (1.0f + __expf(-x));
            hh[half * 16 + rr][c] = x * sg;
        }
    }
    __syncthreads();
    {
        float pa[32][3];
        #pragma unroll
        for (int r = 0; r < 32; ++r)
            #pragma unroll
            for (int cg = 0; cg < 3; ++cg) pa[r][cg] = 0.f;

        for (int k4 = 0; k4 < 32; ++k4) {
            float w[4][3];
            #pragma unroll
            for (int kk = 0; kk < 4; ++kk)
                #pragma unroll
                for (int cg = 0; cg < 3; ++cg)
                    w[kk][cg] = W2[(size_t)(k4 * 4 + kk) * SIXF + t + 256 * cg];
            #pragma unroll
            for (int r = 0; r < 32; ++r) {
                float4 hv = *reinterpret_cast<const float4*>(&hh[r][k4 * 4]);
                #pragma unroll
                for (int cg = 0; cg < 3; ++cg) {
                    pa[r][cg] = fmaf(hv.x, w[0][cg], pa[r][cg]);
                    pa[r][cg] = fmaf(hv.y, w[1][cg], pa[r][cg]);
                    pa[r][cg] = fmaf(hv.z, w[2][cg], pa[r][cg]);
                    pa[r][cg] = fmaf(hv.w, w[3][cg], pa[r][cg]);
                }
            }
        }
        float b2c[3] = { b2[t], b2[t + 256], b2[t + 512] };
        #pragma unroll
        for (int r = 0; r < 32; ++r) {
            if (row0 + r < NN) {
                #pragma unroll
                for (int cg = 0; cg < 3; ++cg)
                    phiw[(size_t)(row0 + r) * SIXF + t + 256 * cg] = f2bf(pa[r][cg] + b2c[cg]);
            }
        }
    }
}

// ---------------- K3: fused edge kernel ----------------
// 32 edges per block (8 per wave, two 4-edge register-tiled GEMM groups).
__global__ __launch_bounds__(256) void edge_kernel(
    const float* __restrict__ re1, const float* __restrict__ re2,
    const float* __restrict__ f1, const float* __restrict__ f2,
    const float* __restrict__ u1v, const float* __restrict__ u2v,
    const int* __restrict__ eidx,
    const u16* __restrict__ phiw, const float* __restrict__ v,
    const float* __restrict__ Wr, const float* __restrict__ br,
    float* __restrict__ out)
{
    __shared__ u16   WrB[K21][SIXF];   // rows 0..19 = Wr (bf16), row 20 = br
    __shared__ float rrs[32][K21];     // rr[e][r], r=20 holds (f1+f2) for br term
    __shared__ float euv[32][6];
    __shared__ int   eid[32][2];
    const int t = threadIdx.x;
    const int e0 = blockIdx.x * 32;

    for (int i = t; i < 20 * SIXF; i += 256) WrB[0][i] = f2bf(Wr[i]);
    for (int c = t; c < SIXF; c += 256)      WrB[20][c] = f2bf(br[c]);
    for (int i = t; i < 32 * K21; i += 256) {
        int el = i / K21, r = i - el * K21;
        int e = e0 + el;
        float a;
        if (r < 20) a = f1[e] * re1[(size_t)e * 20 + r] + f2[e] * re2[(size_t)e * 20 + r];
        else        a = f1[e] + f2[e];
        rrs[el][r] = a;
    }
    if (t < 32) {
        int e = e0 + t;
        eid[t][0] = eidx[e];
        eid[t][1] = eidx[NE + e];
        #pragma unroll
        for (int d = 0; d < 3; ++d) {
            euv[t][d]     = u1v[(size_t)e * 3 + d];
            euv[t][3 + d] = u2v[(size_t)e * 3 + d];
        }
    }
    __syncthreads();

    const int wave = t >> 6, lane = t & 63;
    #pragma unroll 1
    for (int half = 0; half < 2; ++half) {
        const int eg = wave * 8 + half * 4;
        float acc[4][12];
        #pragma unroll
        for (int ea = 0; ea < 4; ++ea)
            #pragma unroll
            for (int cb = 0; cb < 12; ++cb) acc[ea][cb] = 0.f;

        for (int r = 0; r < K21; ++r) {
            float wv[12];
            #pragma unroll
            for (int cc = 0; cc < 6; ++cc) {
                u32 pk = *reinterpret_cast<const u32*>(&WrB[r][cc * 128 + 2 * lane]);
                wv[2 * cc]     = bf2f_lo(pk);
                wv[2 * cc + 1] = bf2f_hi(pk);
            }
            #pragma unroll
            for (int e4 = 0; e4 < 4; ++e4) {
                float a = rrs[eg + e4][r];
                #pragma unroll
                for (int c = 0; c < 12; ++c) acc[e4][c] = fmaf(a, wv[c], acc[e4][c]);
            }
        }

        #pragma unroll 1
        for (int e4 = 0; e4 < 4; ++e4) {
            const int el = eg + e4;
            const int ni = eid[el][0], nj = eid[el][1];
            const float u1x = euv[el][0], u1y = euv[el][1], u1z = euv[el][2];
            const float u2x = euv[el][3], u2y = euv[el][4], u2z = euv[el][5];
            const u16* ph = phiw + (size_t)nj * SIXF + 2 * lane;
            float px[12];
            #pragma unroll
            for (int cc = 0; cc < 6; ++cc) {
                u32 pk = *reinterpret_cast<const u32*>(ph + cc * 128);
                px[2 * cc]     = bf2f_lo(pk);
                px[2 * cc + 1] = bf2f_hi(pk);
            }
            const float* vj = v + (size_t)nj * 384 + 2 * lane;
            float2 va = *reinterpret_cast<const float2*>(vj);
            float2 vb = *reinterpret_cast<const float2*>(vj + 128);
            float2 vc = *reinterpret_cast<const float2*>(vj + 256);
            float* po = out + (size_t)ni * NF + 2 * lane;
            float* pv = out + (size_t)NN * NF + (size_t)ni * 384 + 2 * lane;
            #pragma unroll
            for (int ff = 0; ff < 2; ++ff) {
                float xs   = acc[e4][0 + ff]  * px[0 + ff];
                float xvv  = acc[e4][2 + ff]  * px[2 + ff];
                float xvs1 = acc[e4][4 + ff]  * px[4 + ff];
                float xvs2 = acc[e4][6 + ff]  * px[6 + ff];
                float xvc1 = acc[e4][8 + ff]  * px[8 + ff];
                float xvc2 = acc[e4][10 + ff] * px[10 + ff];
                float a0 = ff ? va.y : va.x;
                float a1 = ff ? vb.y : vb.x;
                float a2 = ff ? vc.y : vc.x;
                float c1x = a1 * u1z - a2 * u1y;
                float c1y = a2 * u1x - a0 * u1z;
                float c1z = a0 * u1y - a1 * u1x;
                float c2x = a1 * u2z - a2 * u2y;
                float c2y = a2 * u2x - a0 * u2z;
                float c2z = a0 * u2y - a1 * u2x;
                float xv0 = a0 * xvv + xvs1 * u1x + xvs2 * u2x + xvc1 * c1x + xvc2 * c2x;
                float xv1 = a1 * xvv + xvs1 * u1y + xvs2 * u2y + xvc1 * c1y + xvc2 * c2y;
                float xv2 = a2 * xvv + xvs1 * u1z + xvs2 * u2z + xvc1 * c1z + xvc2 * c2z;
                unsafeAtomicAdd(po + ff, xs);
                unsafeAtomicAdd(pv + ff, xv0);
                unsafeAtomicAdd(pv + 128 + ff, xv1);
                unsafeAtomicAdd(pv + 256 + ff, xv2);
            }
        }
    }
}

extern "C" void kernel_launch(void* const* d_in, const int* in_sizes, int n_in,
                              void* d_out, int out_size, void* d_ws, size_t ws_size,
                              hipStream_t stream) {
    const float* s   = (const float*)d_in[0];
    const float* v   = (const float*)d_in[1];
    const float* re1 = (const float*)d_in[2];
    const float* re2 = (const float*)d_in[3];
    const float* f1  = (const float*)d_in[4];
    const float* f2  = (const float*)d_in[5];
    const float* u1  = (const float*)d_in[6];
    const float* u2  = (const float*)d_in[7];
    const int*   ei  = (const int*)d_in[8];
    const float* W1  = (const float*)d_in[9];
    const float* b1  = (const float*)d_in[10];
    const float* W2  = (const float*)d_in[11];
    const float* b2  = (const float*)d_in[12];
    const float* Wr  = (const float*)d_in[13];
    const float* br  = (const float*)d_in[14];
    float* out = (float*)d_out;
    u16* phiw = (u16*)d_ws;   // 10000*768 bf16 = 15.36 MB

    init_out_kernel<<<dim3((NN * NF + NN * 3 * NF) / 4 / 256), dim3(256), 0, stream>>>(
        (const float4*)s, (const float4*)v, (float4*)out);
    phi_kernel<<<dim3((NN + 31) / 32), dim3(256), 0, stream>>>(s, W1, b1, W2, b2, phiw);
    edge_kernel<<<dim3(NE / 32), dim3(256), 0, stream>>>(
        re1, re2, f1, f2, u1, u2, ei, phiw, v, Wr, br, out);
}

// Round 4
// 863.589 us; speedup vs baseline: 1.5053x; 1.5053x over previous
//
#include <hip/hip_runtime.h>
#include <hip/hip_bf16.h>

#define NN   10000
#define NE   320000
#define NF   128
#define SIXF 768
#define K21  21

typedef unsigned short u16;
typedef unsigned int   u32;

__device__ __forceinline__ float bf2f_lo(u32 pk) { return __uint_as_float(pk << 16); }
__device__ __forceinline__ float bf2f_hi(u32 pk) { return __uint_as_float(pk & 0xffff0000u); }
__device__ __forceinline__ u16 f2bf(float f) {
    u32 x = __float_as_uint(f);
    return (u16)((x + 0x7fffu + ((x >> 16) & 1u)) >> 16);
}

// ---------------- K0 (fallback only): out = [s ; v] ----------------
__global__ __launch_bounds__(256) void init_out_kernel(
    const float4* __restrict__ s4, const float4* __restrict__ v4, float4* __restrict__ out4)
{
    int i = blockIdx.x * 256 + threadIdx.x;
    if (i < NN * NF / 4) out4[i] = s4[i];
    else                 out4[i] = v4[i - NN * NF / 4];
}

// ---------------- K1: phi = silu(s@W1+b1)@W2+b2 -> bf16 ----------------
__global__ __launch_bounds__(256) void phi_kernel(
    const float* __restrict__ s, const float* __restrict__ W1, const float* __restrict__ b1,
    const float* __restrict__ W2, const float* __restrict__ b2, u16* __restrict__ phiw)
{
    __shared__ float sh[32][NF];
    __shared__ float hh[32][NF];
    const int t = threadIdx.x;
    const int row0 = blockIdx.x * 32;

    for (int i = t; i < 32 * NF / 4; i += 256) {
        int r = i >> 5, c4 = i & 31;
        float4 val = make_float4(0.f, 0.f, 0.f, 0.f);
        if (row0 + r < NN) val = *reinterpret_cast<const float4*>(&s[(size_t)(row0 + r) * NF + c4 * 4]);
        *reinterpret_cast<float4*>(&sh[r][c4 * 4]) = val;
    }
    __syncthreads();
    {
        const int c = t & 127;
        const int half = t >> 7;
        float hacc[16];
        #pragma unroll
        for (int i = 0; i < 16; ++i) hacc[i] = 0.f;
        for (int k4 = 0; k4 < 32; ++k4) {
            float w0 = W1[(k4 * 4 + 0) * NF + c];
            float w1 = W1[(k4 * 4 + 1) * NF + c];
            float w2 = W1[(k4 * 4 + 2) * NF + c];
            float w3 = W1[(k4 * 4 + 3) * NF + c];
            #pragma unroll
            for (int rr = 0; rr < 16; ++rr) {
                float4 sv = *reinterpret_cast<const float4*>(&sh[half * 16 + rr][k4 * 4]);
                hacc[rr] = fmaf(sv.x, w0, hacc[rr]);
                hacc[rr] = fmaf(sv.y, w1, hacc[rr]);
                hacc[rr] = fmaf(sv.z, w2, hacc[rr]);
                hacc[rr] = fmaf(sv.w, w3, hacc[rr]);
            }
        }
        float b1c = b1[c];
        #pragma unroll
        for (int rr = 0; rr < 16; ++rr) {
            float x = hacc[rr] + b1c;
            float sg = 1.0f / (1.0f + __expf(-x));
            hh[half * 16 + rr][c] = x * sg;
        }
    }
    __syncthreads();
    {
        float pa[32][3];
        #pragma unroll
        for (int r = 0; r < 32; ++r)
            #pragma unroll
            for (int cg = 0; cg < 3; ++cg) pa[r][cg] = 0.f;

        for (int k4 = 0; k4 < 32; ++k4) {
            float w[4][3];
            #pragma unroll
            for (int kk = 0; kk < 4; ++kk)
                #pragma unroll
                for (int cg = 0; cg < 3; ++cg)
                    w[kk][cg] = W2[(size_t)(k4 * 4 + kk) * SIXF + t + 256 * cg];
            #pragma unroll
            for (int r = 0; r < 32; ++r) {
                float4 hv = *reinterpret_cast<const float4*>(&hh[r][k4 * 4]);
                #pragma unroll
                for (int cg = 0; cg < 3; ++cg) {
                    pa[r][cg] = fmaf(hv.x, w[0][cg], pa[r][cg]);
                    pa[r][cg] = fmaf(hv.y, w[1][cg], pa[r][cg]);
                    pa[r][cg] = fmaf(hv.z, w[2][cg], pa[r][cg]);
                    pa[r][cg] = fmaf(hv.w, w[3][cg], pa[r][cg]);
                }
            }
        }
        float b2c[3] = { b2[t], b2[t + 256], b2[t + 512] };
        #pragma unroll
        for (int r = 0; r < 32; ++r) {
            if (row0 + r < NN) {
                #pragma unroll
                for (int cg = 0; cg < 3; ++cg)
                    phiw[(size_t)(row0 + r) * SIXF + t + 256 * cg] = f2bf(pa[r][cg] + b2c[cg]);
            }
        }
    }
}

// ---------------- CSR build ----------------
__global__ __launch_bounds__(256) void zero_cnt_kernel(int* __restrict__ cnt) {
    int i = blockIdx.x * 256 + threadIdx.x;
    if (i < NN) cnt[i] = 0;
}

__global__ __launch_bounds__(256) void hist_kernel(const int* __restrict__ eidx, int* __restrict__ cnt) {
    int e = blockIdx.x * 256 + threadIdx.x;
    if (e < NE) atomicAdd(&cnt[eidx[e]], 1);
}

// single block, 256 threads; threads 0..249 own 40 nodes each
__global__ __launch_bounds__(256) void scan_kernel(const int* __restrict__ cnt, int* __restrict__ offs) {
    __shared__ int part[256];
    const int t = threadIdx.x;
    int lsum = 0;
    if (t < 250) {
        #pragma unroll 4
        for (int k = 0; k < 40; ++k) lsum += cnt[t * 40 + k];
    }
    part[t] = lsum;
    __syncthreads();
    if (t == 0) {
        int run = 0;
        for (int i = 0; i < 250; ++i) { int c = part[i]; part[i] = run; run += c; }
    }
    __syncthreads();
    if (t < 250) {
        int run = part[t];
        for (int k = 0; k < 40; ++k) {
            int idx = t * 40 + k;
            offs[idx] = run;          // exclusive start; scatter mutates to end
            run += cnt[idx];
        }
    }
}

__global__ __launch_bounds__(256) void scatter_kernel(
    const int* __restrict__ eidx, int* __restrict__ offs, int* __restrict__ elist) {
    int e = blockIdx.x * 256 + threadIdx.x;
    if (e < NE) {
        int pos = atomicAdd(&offs[eidx[e]], 1);
        elist[pos] = e;
    }
}

// ---------------- K3-new: per-node gather (no output atomics) ----------------
__global__ __launch_bounds__(256) void gather_kernel(
    const float* __restrict__ re1, const float* __restrict__ re2,
    const float* __restrict__ f1, const float* __restrict__ f2,
    const float* __restrict__ u1v, const float* __restrict__ u2v,
    const int* __restrict__ eidx,
    const u16* __restrict__ phiw, const float* __restrict__ v,
    const float* __restrict__ Wr, const float* __restrict__ br,
    const float* __restrict__ s,
    const int* __restrict__ cnt, const int* __restrict__ offs,
    const int* __restrict__ elist,
    float* __restrict__ out)
{
    __shared__ u16   WrB[K21][SIXF];   // 32,256 B  rows 0..19 = Wr bf16, row 20 = br
    __shared__ float rrs[32][K21];     // 2,688 B
    __shared__ float euv[32][6];       //   768 B
    __shared__ int   ejd[32];          //   128 B (j index per staged edge)
    __shared__ float redbuf[4][512];   // 8,192 B cross-wave reduce

    const int t = threadIdx.x;
    const int node = blockIdx.x;
    const int deg   = cnt[node];
    const int end   = offs[node];      // post-scatter = end boundary
    const int start = end - deg;

    for (int i = t; i < 20 * SIXF; i += 256) WrB[0][i] = f2bf(Wr[i]);
    for (int c = t; c < SIXF; c += 256)      WrB[20][c] = f2bf(br[c]);

    const int wave = t >> 6, lane = t & 63;
    float accS[2] = {0.f, 0.f};
    float accV[3][2] = {{0.f,0.f},{0.f,0.f},{0.f,0.f}};

    for (int base = 0; base < deg; base += 32) {
        const int m = min(32, deg - base);
        __syncthreads();   // prior compute done reading rrs/euv/ejd (also covers WrB staging on iter 0)
        for (int i = t; i < m * K21; i += 256) {
            int el = i / K21, r = i - el * K21;
            int e = elist[start + base + el];
            float a;
            if (r < 20) a = f1[e] * re1[(size_t)e * 20 + r] + f2[e] * re2[(size_t)e * 20 + r];
            else        a = f1[e] + f2[e];
            rrs[el][r] = a;
        }
        if (t < m) {
            int e = elist[start + base + t];
            ejd[t] = eidx[NE + e];
            #pragma unroll
            for (int d = 0; d < 3; ++d) {
                euv[t][d]     = u1v[(size_t)e * 3 + d];
                euv[t][3 + d] = u2v[(size_t)e * 3 + d];
            }
        }
        __syncthreads();

        #pragma unroll 1
        for (int half = 0; half < 2; ++half) {
            const int eg = wave * 8 + half * 4;
            if (eg >= m) continue;
            float acc[4][12];
            #pragma unroll
            for (int ea = 0; ea < 4; ++ea)
                #pragma unroll
                for (int cb = 0; cb < 12; ++cb) acc[ea][cb] = 0.f;

            for (int r = 0; r < K21; ++r) {
                float wv[12];
                #pragma unroll
                for (int cc = 0; cc < 6; ++cc) {
                    u32 pk = *reinterpret_cast<const u32*>(&WrB[r][cc * 128 + 2 * lane]);
                    wv[2 * cc]     = bf2f_lo(pk);
                    wv[2 * cc + 1] = bf2f_hi(pk);
                }
                #pragma unroll
                for (int e4 = 0; e4 < 4; ++e4) {
                    float a = rrs[eg + e4][r];
                    #pragma unroll
                    for (int c = 0; c < 12; ++c) acc[e4][c] = fmaf(a, wv[c], acc[e4][c]);
                }
            }

            #pragma unroll 1
            for (int e4 = 0; e4 < 4; ++e4) {
                const int el = eg + e4;
                if (el >= m) break;
                const int nj = ejd[el];
                const float u1x = euv[el][0], u1y = euv[el][1], u1z = euv[el][2];
                const float u2x = euv[el][3], u2y = euv[el][4], u2z = euv[el][5];
                const u16* ph = phiw + (size_t)nj * SIXF + 2 * lane;
                float px[12];
                #pragma unroll
                for (int cc = 0; cc < 6; ++cc) {
                    u32 pk = *reinterpret_cast<const u32*>(ph + cc * 128);
                    px[2 * cc]     = bf2f_lo(pk);
                    px[2 * cc + 1] = bf2f_hi(pk);
                }
                const float* vj = v + (size_t)nj * 384 + 2 * lane;
                float2 va = *reinterpret_cast<const float2*>(vj);
                float2 vb = *reinterpret_cast<const float2*>(vj + 128);
                float2 vc = *reinterpret_cast<const float2*>(vj + 256);
                #pragma unroll
                for (int ff = 0; ff < 2; ++ff) {
                    float xs   = acc[e4][0 + ff]  * px[0 + ff];
                    float xvv  = acc[e4][2 + ff]  * px[2 + ff];
                    float xvs1 = acc[e4][4 + ff]  * px[4 + ff];
                    float xvs2 = acc[e4][6 + ff]  * px[6 + ff];
                    float xvc1 = acc[e4][8 + ff]  * px[8 + ff];
                    float xvc2 = acc[e4][10 + ff] * px[10 + ff];
                    float a0 = ff ? va.y : va.x;
                    float a1 = ff ? vb.y : vb.x;
                    float a2 = ff ? vc.y : vc.x;
                    float c1x = a1 * u1z - a2 * u1y;
                    float c1y = a2 * u1x - a0 * u1z;
                    float c1z = a0 * u1y - a1 * u1x;
                    float c2x = a1 * u2z - a2 * u2y;
                    float c2y = a2 * u2x - a0 * u2z;
                    float c2z = a0 * u2y - a1 * u2x;
                    accS[ff] += xs;
                    accV[0][ff] += a0 * xvv + xvs1 * u1x + xvs2 * u2x + xvc1 * c1x + xvc2 * c2x;
                    accV[1][ff] += a1 * xvv + xvs1 * u1y + xvs2 * u2y + xvc1 * c1y + xvc2 * c2y;
                    accV[2][ff] += a2 * xvv + xvs1 * u1z + xvs2 * u2z + xvc1 * c1z + xvc2 * c2z;
                }
            }
        }
    }

    // cross-wave reduction + single write (base folded in)
    __syncthreads();
    #pragma unroll
    for (int ff = 0; ff < 2; ++ff) {
        redbuf[wave][2 * lane + ff] = accS[ff];
        #pragma unroll
        for (int d = 0; d < 3; ++d)
            redbuf[wave][128 + d * 128 + 2 * lane + ff] = accV[d][ff];
    }
    __syncthreads();
    for (int k = t; k < 512; k += 256) {
        float sum = redbuf[0][k] + redbuf[1][k] + redbuf[2][k] + redbuf[3][k];
        if (k < NF) {
            out[(size_t)node * NF + k] = s[(size_t)node * NF + k] + sum;
        } else {
            int kv = k - NF;   // d*128 + f
            out[(size_t)NN * NF + (size_t)node * 384 + kv] = v[(size_t)node * 384 + kv] + sum;
        }
    }
}

// ---------------- K3-fallback: atomic edge kernel (proven) ----------------
__global__ __launch_bounds__(256) void edge_kernel(
    const float* __restrict__ re1, const float* __restrict__ re2,
    const float* __restrict__ f1, const float* __restrict__ f2,
    const float* __restrict__ u1v, const float* __restrict__ u2v,
    const int* __restrict__ eidx,
    const u16* __restrict__ phiw, const float* __restrict__ v,
    const float* __restrict__ Wr, const float* __restrict__ br,
    float* __restrict__ out)
{
    __shared__ u16   WrB[K21][SIXF];
    __shared__ float rrs[32][K21];
    __shared__ float euv[32][6];
    __shared__ int   eid[32][2];
    const int t = threadIdx.x;
    const int e0 = blockIdx.x * 32;

    for (int i = t; i < 20 * SIXF; i += 256) WrB[0][i] = f2bf(Wr[i]);
    for (int c = t; c < SIXF; c += 256)      WrB[20][c] = f2bf(br[c]);
    for (int i = t; i < 32 * K21; i += 256) {
        int el = i / K21, r = i - el * K21;
        int e = e0 + el;
        float a;
        if (r < 20) a = f1[e] * re1[(size_t)e * 20 + r] + f2[e] * re2[(size_t)e * 20 + r];
        else        a = f1[e] + f2[e];
        rrs[el][r] = a;
    }
    if (t < 32) {
        int e = e0 + t;
        eid[t][0] = eidx[e];
        eid[t][1] = eidx[NE + e];
        #pragma unroll
        for (int d = 0; d < 3; ++d) {
            euv[t][d]     = u1v[(size_t)e * 3 + d];
            euv[t][3 + d] = u2v[(size_t)e * 3 + d];
        }
    }
    __syncthreads();

    const int wave = t >> 6, lane = t & 63;
    #pragma unroll 1
    for (int half = 0; half < 2; ++half) {
        const int eg = wave * 8 + half * 4;
        float acc[4][12];
        #pragma unroll
        for (int ea = 0; ea < 4; ++ea)
            #pragma unroll
            for (int cb = 0; cb < 12; ++cb) acc[ea][cb] = 0.f;

        for (int r = 0; r < K21; ++r) {
            float wv[12];
            #pragma unroll
            for (int cc = 0; cc < 6; ++cc) {
                u32 pk = *reinterpret_cast<const u32*>(&WrB[r][cc * 128 + 2 * lane]);
                wv[2 * cc]     = bf2f_lo(pk);
                wv[2 * cc + 1] = bf2f_hi(pk);
            }
            #pragma unroll
            for (int e4 = 0; e4 < 4; ++e4) {
                float a = rrs[eg + e4][r];
                #pragma unroll
                for (int c = 0; c < 12; ++c) acc[e4][c] = fmaf(a, wv[c], acc[e4][c]);
            }
        }

        #pragma unroll 1
        for (int e4 = 0; e4 < 4; ++e4) {
            const int el = eg + e4;
            const int ni = eid[el][0], nj = eid[el][1];
            const float u1x = euv[el][0], u1y = euv[el][1], u1z = euv[el][2];
            const float u2x = euv[el][3], u2y = euv[el][4], u2z = euv[el][5];
            const u16* ph = phiw + (size_t)nj * SIXF + 2 * lane;
            float px[12];
            #pragma unroll
            for (int cc = 0; cc < 6; ++cc) {
                u32 pk = *reinterpret_cast<const u32*>(ph + cc * 128);
                px[2 * cc]     = bf2f_lo(pk);
                px[2 * cc + 1] = bf2f_hi(pk);
            }
            const float* vj = v + (size_t)nj * 384 + 2 * lane;
            float2 va = *reinterpret_cast<const float2*>(vj);
            float2 vb = *reinterpret_cast<const float2*>(vj + 128);
            float2 vc = *reinterpret_cast<const float2*>(vj + 256);
            float* po = out + (size_t)ni * NF + 2 * lane;
            float* pv = out + (size_t)NN * NF + (size_t)ni * 384 + 2 * lane;
            #pragma unroll
            for (int ff = 0; ff < 2; ++ff) {
                float xs   = acc[e4][0 + ff]  * px[0 + ff];
                float xvv  = acc[e4][2 + ff]  * px[2 + ff];
                float xvs1 = acc[e4][4 + ff]  * px[4 + ff];
                float xvs2 = acc[e4][6 + ff]  * px[6 + ff];
                float xvc1 = acc[e4][8 + ff]  * px[8 + ff];
                float xvc2 = acc[e4][10 + ff] * px[10 + ff];
                float a0 = ff ? va.y : va.x;
                float a1 = ff ? vb.y : vb.x;
                float a2 = ff ? vc.y : vc.x;
                float c1x = a1 * u1z - a2 * u1y;
                float c1y = a2 * u1x - a0 * u1z;
                float c1z = a0 * u1y - a1 * u1x;
                float c2x = a1 * u2z - a2 * u2y;
                float c2y = a2 * u2x - a0 * u2z;
                float c2z = a0 * u2y - a1 * u2x;
                float xv0 = a0 * xvv + xvs1 * u1x + xvs2 * u2x + xvc1 * c1x + xvc2 * c2x;
                float xv1 = a1 * xvv + xvs1 * u1y + xvs2 * u2y + xvc1 * c1y + xvc2 * c2y;
                float xv2 = a2 * xvv + xvs1 * u1z + xvs2 * u2z + xvc1 * c1z + xvc2 * c2z;
                unsafeAtomicAdd(po + ff, xs);
                unsafeAtomicAdd(pv + ff, xv0);
                unsafeAtomicAdd(pv + 128 + ff, xv1);
                unsafeAtomicAdd(pv + 256 + ff, xv2);
            }
        }
    }
}

extern "C" void kernel_launch(void* const* d_in, const int* in_sizes, int n_in,
                              void* d_out, int out_size, void* d_ws, size_t ws_size,
                              hipStream_t stream) {
    const float* s   = (const float*)d_in[0];
    const float* v   = (const float*)d_in[1];
    const float* re1 = (const float*)d_in[2];
    const float* re2 = (const float*)d_in[3];
    const float* f1  = (const float*)d_in[4];
    const float* f2  = (const float*)d_in[5];
    const float* u1  = (const float*)d_in[6];
    const float* u2  = (const float*)d_in[7];
    const int*   ei  = (const int*)d_in[8];
    const float* W1  = (const float*)d_in[9];
    const float* b1  = (const float*)d_in[10];
    const float* W2  = (const float*)d_in[11];
    const float* b2  = (const float*)d_in[12];
    const float* Wr  = (const float*)d_in[13];
    const float* br  = (const float*)d_in[14];
    float* out = (float*)d_out;

    u16* phiw  = (u16*)d_ws;                                   // 15,360,000 B
    int* cnt   = (int*)((char*)d_ws + (size_t)NN * SIXF * 2);  // 40,000 B
    int* offs  = cnt + NN;                                      // 40,000 B
    int* elist = offs + NN;                                     // 1,280,000 B
    const size_t needed = (size_t)NN * SIXF * 2 + 2u * NN * 4 + (size_t)NE * 4;

    phi_kernel<<<dim3((NN + 31) / 32), dim3(256), 0, stream>>>(s, W1, b1, W2, b2, phiw);

    if (ws_size >= needed) {
        zero_cnt_kernel<<<dim3((NN + 255) / 256), dim3(256), 0, stream>>>(cnt);
        hist_kernel<<<dim3((NE + 255) / 256), dim3(256), 0, stream>>>(ei, cnt);
        scan_kernel<<<dim3(1), dim3(256), 0, stream>>>(cnt, offs);
        scatter_kernel<<<dim3((NE + 255) / 256), dim3(256), 0, stream>>>(ei, offs, elist);
        gather_kernel<<<dim3(NN), dim3(256), 0, stream>>>(
            re1, re2, f1, f2, u1, u2, ei, phiw, v, Wr, br, s, cnt, offs, elist, out);
    } else {
        init_out_kernel<<<dim3((NN * NF + NN * 3 * NF) / 4 / 256), dim3(256), 0, stream>>>(
            (const float4*)s, (const float4*)v, (float4*)out);
        edge_kernel<<<dim3(NE / 32), dim3(256), 0, stream>>>(
            re1, re2, f1, f2, u1, u2, ei, phiw, v, Wr, br, out);
    }
}

// Round 5
// 796.321 us; speedup vs baseline: 1.6324x; 1.0845x over previous
//
#include <hip/hip_runtime.h>
#include <hip/hip_bf16.h>

#define NN   10000
#define NE   320000
#define NF   128
#define SIXF 768
#define K21  21

typedef unsigned short u16;
typedef unsigned int   u32;

__device__ __forceinline__ float bf2f_lo(u32 pk) { return __uint_as_float(pk << 16); }
__device__ __forceinline__ float bf2f_hi(u32 pk) { return __uint_as_float(pk & 0xffff0000u); }
__device__ __forceinline__ u16 f2bf(float f) {
    u32 x = __float_as_uint(f);
    return (u16)((x + 0x7fffu + ((x >> 16) & 1u)) >> 16);
}

// ---------------- K0 (fallback only): out = [s ; v] ----------------
__global__ __launch_bounds__(256) void init_out_kernel(
    const float4* __restrict__ s4, const float4* __restrict__ v4, float4* __restrict__ out4)
{
    int i = blockIdx.x * 256 + threadIdx.x;
    if (i < NN * NF / 4) out4[i] = s4[i];
    else                 out4[i] = v4[i - NN * NF / 4];
}

// ---------------- K1: phi = silu(s@W1+b1)@W2+b2 -> bf16 ----------------
__global__ __launch_bounds__(256) void phi_kernel(
    const float* __restrict__ s, const float* __restrict__ W1, const float* __restrict__ b1,
    const float* __restrict__ W2, const float* __restrict__ b2, u16* __restrict__ phiw)
{
    __shared__ float sh[32][NF];
    __shared__ float hh[32][NF];
    const int t = threadIdx.x;
    const int row0 = blockIdx.x * 32;

    for (int i = t; i < 32 * NF / 4; i += 256) {
        int r = i >> 5, c4 = i & 31;
        float4 val = make_float4(0.f, 0.f, 0.f, 0.f);
        if (row0 + r < NN) val = *reinterpret_cast<const float4*>(&s[(size_t)(row0 + r) * NF + c4 * 4]);
        *reinterpret_cast<float4*>(&sh[r][c4 * 4]) = val;
    }
    __syncthreads();
    {
        const int c = t & 127;
        const int half = t >> 7;
        float hacc[16];
        #pragma unroll
        for (int i = 0; i < 16; ++i) hacc[i] = 0.f;
        for (int k4 = 0; k4 < 32; ++k4) {
            float w0 = W1[(k4 * 4 + 0) * NF + c];
            float w1 = W1[(k4 * 4 + 1) * NF + c];
            float w2 = W1[(k4 * 4 + 2) * NF + c];
            float w3 = W1[(k4 * 4 + 3) * NF + c];
            #pragma unroll
            for (int rr = 0; rr < 16; ++rr) {
                float4 sv = *reinterpret_cast<const float4*>(&sh[half * 16 + rr][k4 * 4]);
                hacc[rr] = fmaf(sv.x, w0, hacc[rr]);
                hacc[rr] = fmaf(sv.y, w1, hacc[rr]);
                hacc[rr] = fmaf(sv.z, w2, hacc[rr]);
                hacc[rr] = fmaf(sv.w, w3, hacc[rr]);
            }
        }
        float b1c = b1[c];
        #pragma unroll
        for (int rr = 0; rr < 16; ++rr) {
            float x = hacc[rr] + b1c;
            float sg = 1.0f / (1.0f + __expf(-x));
            hh[half * 16 + rr][c] = x * sg;
        }
    }
    __syncthreads();
    {
        float pa[32][3];
        #pragma unroll
        for (int r = 0; r < 32; ++r)
            #pragma unroll
            for (int cg = 0; cg < 3; ++cg) pa[r][cg] = 0.f;

        for (int k4 = 0; k4 < 32; ++k4) {
            float w[4][3];
            #pragma unroll
            for (int kk = 0; kk < 4; ++kk)
                #pragma unroll
                for (int cg = 0; cg < 3; ++cg)
                    w[kk][cg] = W2[(size_t)(k4 * 4 + kk) * SIXF + t + 256 * cg];
            #pragma unroll
            for (int r = 0; r < 32; ++r) {
                float4 hv = *reinterpret_cast<const float4*>(&hh[r][k4 * 4]);
                #pragma unroll
                for (int cg = 0; cg < 3; ++cg) {
                    pa[r][cg] = fmaf(hv.x, w[0][cg], pa[r][cg]);
                    pa[r][cg] = fmaf(hv.y, w[1][cg], pa[r][cg]);
                    pa[r][cg] = fmaf(hv.z, w[2][cg], pa[r][cg]);
                    pa[r][cg] = fmaf(hv.w, w[3][cg], pa[r][cg]);
                }
            }
        }
        float b2c[3] = { b2[t], b2[t + 256], b2[t + 512] };
        #pragma unroll
        for (int r = 0; r < 32; ++r) {
            if (row0 + r < NN) {
                #pragma unroll
                for (int cg = 0; cg < 3; ++cg)
                    phiw[(size_t)(row0 + r) * SIXF + t + 256 * cg] = f2bf(pa[r][cg] + b2c[cg]);
            }
        }
    }
}

// ---------------- prep kernels ----------------
// wrb[21][768] bf16: rows 0..19 = Wr, row 20 = br
__global__ __launch_bounds__(256) void prep_wrb_kernel(
    const float* __restrict__ Wr, const float* __restrict__ br, u16* __restrict__ wrb)
{
    int i = blockIdx.x * 256 + threadIdx.x;
    if (i < 21 * SIXF) wrb[i] = f2bf(i < 20 * SIXF ? Wr[i] : br[i - 20 * SIXF]);
}

__global__ __launch_bounds__(256) void prep_vbf_kernel(
    const float* __restrict__ v, u16* __restrict__ vbf)
{
    int i = blockIdx.x * 256 + threadIdx.x;
    if (i < NN * 384) vbf[i] = f2bf(v[i]);
}

// ---------------- CSR build ----------------
__global__ __launch_bounds__(256) void zero_cnt_kernel(int* __restrict__ cnt) {
    int i = blockIdx.x * 256 + threadIdx.x;
    if (i < NN) cnt[i] = 0;
}

__global__ __launch_bounds__(256) void hist_kernel(const int* __restrict__ eidx, int* __restrict__ cnt) {
    int e = blockIdx.x * 256 + threadIdx.x;
    if (e < NE) atomicAdd(&cnt[eidx[e]], 1);
}

__global__ __launch_bounds__(256) void scan_kernel(const int* __restrict__ cnt, int* __restrict__ offs) {
    __shared__ int part[256];
    const int t = threadIdx.x;
    int lsum = 0;
    if (t < 250) {
        #pragma unroll 4
        for (int k = 0; k < 40; ++k) lsum += cnt[t * 40 + k];
    }
    part[t] = lsum;
    __syncthreads();
    if (t == 0) {
        int run = 0;
        for (int i = 0; i < 250; ++i) { int c = part[i]; part[i] = run; run += c; }
    }
    __syncthreads();
    if (t < 250) {
        int run = part[t];
        for (int k = 0; k < 40; ++k) {
            int idx = t * 40 + k;
            offs[idx] = run;          // exclusive start; scatter mutates to end
            run += cnt[idx];
        }
    }
}

__global__ __launch_bounds__(256) void scatter_kernel(
    const int* __restrict__ eidx, int* __restrict__ offs, int* __restrict__ elist) {
    int e = blockIdx.x * 256 + threadIdx.x;
    if (e < NE) {
        int pos = atomicAdd(&offs[eidx[e]], 1);
        elist[pos] = e;
    }
}

// ---------------- K3: per-node gather (no output atomics, no spills) ----------------
// LDS: WrB 32256 + scratch 8192 = 40448 B -> 4 blocks/CU.
// __launch_bounds__(256,4): VGPR cap 128 >= ~100 live (acc48+px12+v6+u6+accSV8+addr).
template<bool USE_VBF>
__global__ __launch_bounds__(256, 4) void gather_kernel(
    const float* __restrict__ re1, const float* __restrict__ re2,
    const float* __restrict__ f1, const float* __restrict__ f2,
    const float* __restrict__ u1v, const float* __restrict__ u2v,
    const int* __restrict__ eidx,
    const u16* __restrict__ phiw, const float* __restrict__ v,
    const u16* __restrict__ vbf, const u16* __restrict__ wrb,
    const float* __restrict__ s,
    const int* __restrict__ cnt, const int* __restrict__ offs,
    const int* __restrict__ elist,
    float* __restrict__ out)
{
    __shared__ u16   WrB[K21][SIXF];     // 32,256 B (bf16, row 20 = br)
    __shared__ float smem[2048];         //  8,192 B — staging arrays aliased with redbuf
    float (*rrs)[K21] = (float(*)[K21])smem;            // 672 floats
    float (*euv)[6]   = (float(*)[6])(smem + 672);      // 192 floats
    int*   ejd        = (int*)(smem + 864);             //  32 ints
    float (*redbuf)[512] = (float(*)[512])smem;         // full 2048 (used after final sync)

    const int t = threadIdx.x;
    const int node = blockIdx.x;
    const int deg   = cnt[node];
    const int end   = offs[node];        // post-scatter = end boundary
    const int start = end - deg;

    {   // stage precomputed bf16 Wr/br: linear 8064 u32 copy
        const u32* wg = (const u32*)wrb;
        u32* wl = (u32*)&WrB[0][0];
        for (int i = t; i < 8064; i += 256) wl[i] = wg[i];
    }

    const int wave = t >> 6, lane = t & 63;
    float accS[2] = {0.f, 0.f};
    float accV[3][2] = {{0.f,0.f},{0.f,0.f},{0.f,0.f}};

    for (int base = 0; base < deg; base += 32) {
        const int m = min(32, deg - base);
        __syncthreads();   // prior compute done reading rrs/euv/ejd (covers WrB staging on iter 0)
        for (int i = t; i < m * K21; i += 256) {
            int el = i / K21, r = i - el * K21;
            int e = elist[start + base + el];
            float a;
            if (r < 20) a = f1[e] * re1[(size_t)e * 20 + r] + f2[e] * re2[(size_t)e * 20 + r];
            else        a = f1[e] + f2[e];
            rrs[el][r] = a;
        }
        if (t < m) {
            int e = elist[start + base + t];
            ejd[t] = eidx[NE + e];
            #pragma unroll
            for (int d = 0; d < 3; ++d) {
                euv[t][d]     = u1v[(size_t)e * 3 + d];
                euv[t][3 + d] = u2v[(size_t)e * 3 + d];
            }
        }
        __syncthreads();

        #pragma unroll 1
        for (int half = 0; half < 2; ++half) {
            const int eg = wave * 8 + half * 4;
            if (eg >= m) continue;
            float acc[4][12];
            #pragma unroll
            for (int ea = 0; ea < 4; ++ea)
                #pragma unroll
                for (int cb = 0; cb < 12; ++cb) acc[ea][cb] = 0.f;

            for (int r = 0; r < K21; ++r) {
                float wv[12];
                #pragma unroll
                for (int cc = 0; cc < 6; ++cc) {
                    u32 pk = *reinterpret_cast<const u32*>(&WrB[r][cc * 128 + 2 * lane]);
                    wv[2 * cc]     = bf2f_lo(pk);
                    wv[2 * cc + 1] = bf2f_hi(pk);
                }
                #pragma unroll
                for (int e4 = 0; e4 < 4; ++e4) {
                    float a = rrs[eg + e4][r];
                    #pragma unroll
                    for (int c = 0; c < 12; ++c) acc[e4][c] = fmaf(a, wv[c], acc[e4][c]);
                }
            }

            #pragma unroll 1
            for (int e4 = 0; e4 < 4; ++e4) {
                const int el = eg + e4;
                if (el >= m) break;
                const int nj = ejd[el];
                const float u1x = euv[el][0], u1y = euv[el][1], u1z = euv[el][2];
                const float u2x = euv[el][3], u2y = euv[el][4], u2z = euv[el][5];
                const u16* ph = phiw + (size_t)nj * SIXF + 2 * lane;
                float px[12];
                #pragma unroll
                for (int cc = 0; cc < 6; ++cc) {
                    u32 pk = *reinterpret_cast<const u32*>(ph + cc * 128);
                    px[2 * cc]     = bf2f_lo(pk);
                    px[2 * cc + 1] = bf2f_hi(pk);
                }
                float2 va, vb, vc;
                if (USE_VBF) {
                    const u16* vj = vbf + (size_t)nj * 384 + 2 * lane;
                    u32 p0 = *reinterpret_cast<const u32*>(vj);
                    u32 p1 = *reinterpret_cast<const u32*>(vj + 128);
                    u32 p2 = *reinterpret_cast<const u32*>(vj + 256);
                    va = make_float2(bf2f_lo(p0), bf2f_hi(p0));
                    vb = make_float2(bf2f_lo(p1), bf2f_hi(p1));
                    vc = make_float2(bf2f_lo(p2), bf2f_hi(p2));
                } else {
                    const float* vj = v + (size_t)nj * 384 + 2 * lane;
                    va = *reinterpret_cast<const float2*>(vj);
                    vb = *reinterpret_cast<const float2*>(vj + 128);
                    vc = *reinterpret_cast<const float2*>(vj + 256);
                }
                #pragma unroll
                for (int ff = 0; ff < 2; ++ff) {
                    float xs   = acc[e4][0 + ff]  * px[0 + ff];
                    float xvv  = acc[e4][2 + ff]  * px[2 + ff];
                    float xvs1 = acc[e4][4 + ff]  * px[4 + ff];
                    float xvs2 = acc[e4][6 + ff]  * px[6 + ff];
                    float xvc1 = acc[e4][8 + ff]  * px[8 + ff];
                    float xvc2 = acc[e4][10 + ff] * px[10 + ff];
                    float a0 = ff ? va.y : va.x;
                    float a1 = ff ? vb.y : vb.x;
                    float a2 = ff ? vc.y : vc.x;
                    float c1x = a1 * u1z - a2 * u1y;
                    float c1y = a2 * u1x - a0 * u1z;
                    float c1z = a0 * u1y - a1 * u1x;
                    float c2x = a1 * u2z - a2 * u2y;
                    float c2y = a2 * u2x - a0 * u2z;
                    float c2z = a0 * u2y - a1 * u2x;
                    accS[ff] += xs;
                    accV[0][ff] += a0 * xvv + xvs1 * u1x + xvs2 * u2x + xvc1 * c1x + xvc2 * c2x;
                    accV[1][ff] += a1 * xvv + xvs1 * u1y + xvs2 * u2y + xvc1 * c1y + xvc2 * c2y;
                    accV[2][ff] += a2 * xvv + xvs1 * u1z + xvs2 * u2z + xvc1 * c1z + xvc2 * c2z;
                }
            }
        }
    }

    // cross-wave reduction + single write (s/v base folded in)
    __syncthreads();
    #pragma unroll
    for (int ff = 0; ff < 2; ++ff) {
        redbuf[wave][2 * lane + ff] = accS[ff];
        #pragma unroll
        for (int d = 0; d < 3; ++d)
            redbuf[wave][128 + d * 128 + 2 * lane + ff] = accV[d][ff];
    }
    __syncthreads();
    for (int k = t; k < 512; k += 256) {
        float sum = redbuf[0][k] + redbuf[1][k] + redbuf[2][k] + redbuf[3][k];
        if (k < NF) {
            out[(size_t)node * NF + k] = s[(size_t)node * NF + k] + sum;
        } else {
            int kv = k - NF;   // d*128 + f
            out[(size_t)NN * NF + (size_t)node * 384 + kv] = v[(size_t)node * 384 + kv] + sum;
        }
    }
}

// ---------------- K3-fallback: atomic edge kernel (proven) ----------------
__global__ __launch_bounds__(256) void edge_kernel(
    const float* __restrict__ re1, const float* __restrict__ re2,
    const float* __restrict__ f1, const float* __restrict__ f2,
    const float* __restrict__ u1v, const float* __restrict__ u2v,
    const int* __restrict__ eidx,
    const u16* __restrict__ phiw, const float* __restrict__ v,
    const float* __restrict__ Wr, const float* __restrict__ br,
    float* __restrict__ out)
{
    __shared__ u16   WrB[K21][SIXF];
    __shared__ float rrs[32][K21];
    __shared__ float euv[32][6];
    __shared__ int   eid[32][2];
    const int t = threadIdx.x;
    const int e0 = blockIdx.x * 32;

    for (int i = t; i < 20 * SIXF; i += 256) WrB[0][i] = f2bf(Wr[i]);
    for (int c = t; c < SIXF; c += 256)      WrB[20][c] = f2bf(br[c]);
    for (int i = t; i < 32 * K21; i += 256) {
        int el = i / K21, r = i - el * K21;
        int e = e0 + el;
        float a;
        if (r < 20) a = f1[e] * re1[(size_t)e * 20 + r] + f2[e] * re2[(size_t)e * 20 + r];
        else        a = f1[e] + f2[e];
        rrs[el][r] = a;
    }
    if (t < 32) {
        int e = e0 + t;
        eid[t][0] = eidx[e];
        eid[t][1] = eidx[NE + e];
        #pragma unroll
        for (int d = 0; d < 3; ++d) {
            euv[t][d]     = u1v[(size_t)e * 3 + d];
            euv[t][3 + d] = u2v[(size_t)e * 3 + d];
        }
    }
    __syncthreads();

    const int wave = t >> 6, lane = t & 63;
    #pragma unroll 1
    for (int half = 0; half < 2; ++half) {
        const int eg = wave * 8 + half * 4;
        float acc[4][12];
        #pragma unroll
        for (int ea = 0; ea < 4; ++ea)
            #pragma unroll
            for (int cb = 0; cb < 12; ++cb) acc[ea][cb] = 0.f;

        for (int r = 0; r < K21; ++r) {
            float wv[12];
            #pragma unroll
            for (int cc = 0; cc < 6; ++cc) {
                u32 pk = *reinterpret_cast<const u32*>(&WrB[r][cc * 128 + 2 * lane]);
                wv[2 * cc]     = bf2f_lo(pk);
                wv[2 * cc + 1] = bf2f_hi(pk);
            }
            #pragma unroll
            for (int e4 = 0; e4 < 4; ++e4) {
                float a = rrs[eg + e4][r];
                #pragma unroll
                for (int c = 0; c < 12; ++c) acc[e4][c] = fmaf(a, wv[c], acc[e4][c]);
            }
        }

        #pragma unroll 1
        for (int e4 = 0; e4 < 4; ++e4) {
            const int el = eg + e4;
            const int ni = eid[el][0], nj = eid[el][1];
            const float u1x = euv[el][0], u1y = euv[el][1], u1z = euv[el][2];
            const float u2x = euv[el][3], u2y = euv[el][4], u2z = euv[el][5];
            const u16* ph = phiw + (size_t)nj * SIXF + 2 * lane;
            float px[12];
            #pragma unroll
            for (int cc = 0; cc < 6; ++cc) {
                u32 pk = *reinterpret_cast<const u32*>(ph + cc * 128);
                px[2 * cc]     = bf2f_lo(pk);
                px[2 * cc + 1] = bf2f_hi(pk);
            }
            const float* vj = v + (size_t)nj * 384 + 2 * lane;
            float2 va = *reinterpret_cast<const float2*>(vj);
            float2 vb = *reinterpret_cast<const float2*>(vj + 128);
            float2 vc = *reinterpret_cast<const float2*>(vj + 256);
            float* po = out + (size_t)ni * NF + 2 * lane;
            float* pv = out + (size_t)NN * NF + (size_t)ni * 384 + 2 * lane;
            #pragma unroll
            for (int ff = 0; ff < 2; ++ff) {
                float xs   = acc[e4][0 + ff]  * px[0 + ff];
                float xvv  = acc[e4][2 + ff]  * px[2 + ff];
                float xvs1 = acc[e4][4 + ff]  * px[4 + ff];
                float xvs2 = acc[e4][6 + ff]  * px[6 + ff];
                float xvc1 = acc[e4][8 + ff]  * px[8 + ff];
                float xvc2 = acc[e4][10 + ff] * px[10 + ff];
                float a0 = ff ? va.y : va.x;
                float a1 = ff ? vb.y : vb.x;
                float a2 = ff ? vc.y : vc.x;
                float c1x = a1 * u1z - a2 * u1y;
                float c1y = a2 * u1x - a0 * u1z;
                float c1z = a0 * u1y - a1 * u1x;
                float c2x = a1 * u2z - a2 * u2y;
                float c2y = a2 * u2x - a0 * u2z;
                float c2z = a0 * u2y - a1 * u2x;
                float xv0 = a0 * xvv + xvs1 * u1x + xvs2 * u2x + xvc1 * c1x + xvc2 * c2x;
                float xv1 = a1 * xvv + xvs1 * u1y + xvs2 * u2y + xvc1 * c1y + xvc2 * c2y;
                float xv2 = a2 * xvv + xvs1 * u1z + xvs2 * u2z + xvc1 * c1z + xvc2 * c2z;
                unsafeAtomicAdd(po + ff, xs);
                unsafeAtomicAdd(pv + ff, xv0);
                unsafeAtomicAdd(pv + 128 + ff, xv1);
                unsafeAtomicAdd(pv + 256 + ff, xv2);
            }
        }
    }
}

extern "C" void kernel_launch(void* const* d_in, const int* in_sizes, int n_in,
                              void* d_out, int out_size, void* d_ws, size_t ws_size,
                              hipStream_t stream) {
    const float* s   = (const float*)d_in[0];
    const float* v   = (const float*)d_in[1];
    const float* re1 = (const float*)d_in[2];
    const float* re2 = (const float*)d_in[3];
    const float* f1  = (const float*)d_in[4];
    const float* f2  = (const float*)d_in[5];
    const float* u1  = (const float*)d_in[6];
    const float* u2  = (const float*)d_in[7];
    const int*   ei  = (const int*)d_in[8];
    const float* W1  = (const float*)d_in[9];
    const float* b1  = (const float*)d_in[10];
    const float* W2  = (const float*)d_in[11];
    const float* b2  = (const float*)d_in[12];
    const float* Wr  = (const float*)d_in[13];
    const float* br  = (const float*)d_in[14];
    float* out = (float*)d_out;

    const size_t PHI_B  = (size_t)NN * SIXF * 2;   // 15,360,000
    const size_t VBF_B  = (size_t)NN * 384 * 2;    //  7,680,000
    const size_t CNT_B  = (size_t)NN * 4;          //     40,000
    const size_t EL_B   = (size_t)NE * 4;          //  1,280,000
    const size_t WRB_B  = (size_t)21 * SIXF * 2;   //     32,256

    const size_t need_full = PHI_B + VBF_B + 2 * CNT_B + EL_B + WRB_B;  // 24.43 MB
    const size_t need_csr  = PHI_B + 2 * CNT_B + EL_B + WRB_B;          // 16.75 MB

    u16* phiw = (u16*)d_ws;
    phi_kernel<<<dim3((NN + 31) / 32), dim3(256), 0, stream>>>(s, W1, b1, W2, b2, phiw);

    if (ws_size >= need_full) {
        u16* vbf   = (u16*)((char*)d_ws + PHI_B);
        int* cnt   = (int*)((char*)d_ws + PHI_B + VBF_B);
        int* offs  = cnt + NN;
        int* elist = offs + NN;
        u16* wrb   = (u16*)((char*)elist + EL_B);

        prep_wrb_kernel<<<dim3((21 * SIXF + 255) / 256), dim3(256), 0, stream>>>(Wr, br, wrb);
        prep_vbf_kernel<<<dim3((NN * 384 + 255) / 256), dim3(256), 0, stream>>>(v, vbf);
        zero_cnt_kernel<<<dim3((NN + 255) / 256), dim3(256), 0, stream>>>(cnt);
        hist_kernel<<<dim3((NE + 255) / 256), dim3(256), 0, stream>>>(ei, cnt);
        scan_kernel<<<dim3(1), dim3(256), 0, stream>>>(cnt, offs);
        scatter_kernel<<<dim3((NE + 255) / 256), dim3(256), 0, stream>>>(ei, offs, elist);
        gather_kernel<true><<<dim3(NN), dim3(256), 0, stream>>>(
            re1, re2, f1, f2, u1, u2, ei, phiw, v, vbf, wrb, s, cnt, offs, elist, out);
    } else if (ws_size >= need_csr) {
        int* cnt   = (int*)((char*)d_ws + PHI_B);
        int* offs  = cnt + NN;
        int* elist = offs + NN;
        u16* wrb   = (u16*)((char*)elist + EL_B);

        prep_wrb_kernel<<<dim3((21 * SIXF + 255) / 256), dim3(256), 0, stream>>>(Wr, br, wrb);
        zero_cnt_kernel<<<dim3((NN + 255) / 256), dim3(256), 0, stream>>>(cnt);
        hist_kernel<<<dim3((NE + 255) / 256), dim3(256), 0, stream>>>(ei, cnt);
        scan_kernel<<<dim3(1), dim3(256), 0, stream>>>(cnt, offs);
        scatter_kernel<<<dim3((NE + 255) / 256), dim3(256), 0, stream>>>(ei, offs, elist);
        gather_kernel<false><<<dim3(NN), dim3(256), 0, stream>>>(
            re1, re2, f1, f2, u1, u2, ei, phiw, v, (const u16*)nullptr, wrb, s, cnt, offs, elist, out);
    } else {
        init_out_kernel<<<dim3((NN * NF + NN * 3 * NF) / 4 / 256), dim3(256), 0, stream>>>(
            (const float4*)s, (const float4*)v, (float4*)out);
        edge_kernel<<<dim3(NE / 32), dim3(256), 0, stream>>>(
            re1, re2, f1, f2, u1, u2, ei, phiw, v, Wr, br, out);
    }
}

// Round 6
// 539.661 us; speedup vs baseline: 2.4088x; 1.4756x over previous
//
#include <hip/hip_runtime.h>
#include <hip/hip_bf16.h>

#define NN   10000
#define NE   320000
#define NF   128
#define SIXF 768
#define K21  21

typedef unsigned short u16;
typedef unsigned int   u32;

__device__ __forceinline__ float bf2f_lo(u32 pk) { return __uint_as_float(pk << 16); }
__device__ __forceinline__ float bf2f_hi(u32 pk) { return __uint_as_float(pk & 0xffff0000u); }
__device__ __forceinline__ u16 f2bf(float f) {
    u32 x = __float_as_uint(f);
    return (u16)((x + 0x7fffu + ((x >> 16) & 1u)) >> 16);
}

// ---------------- K0 (fallback only): out = [s ; v] ----------------
__global__ __launch_bounds__(256) void init_out_kernel(
    const float4* __restrict__ s4, const float4* __restrict__ v4, float4* __restrict__ out4)
{
    int i = blockIdx.x * 256 + threadIdx.x;
    if (i < NN * NF / 4) out4[i] = s4[i];
    else                 out4[i] = v4[i - NN * NF / 4];
}

// ---------------- K1: phi = silu(s@W1+b1)@W2+b2 -> bf16 ----------------
__global__ __launch_bounds__(256) void phi_kernel(
    const float* __restrict__ s, const float* __restrict__ W1, const float* __restrict__ b1,
    const float* __restrict__ W2, const float* __restrict__ b2, u16* __restrict__ phiw)
{
    __shared__ float sh[32][NF];
    __shared__ float hh[32][NF];
    const int t = threadIdx.x;
    const int row0 = blockIdx.x * 32;

    for (int i = t; i < 32 * NF / 4; i += 256) {
        int r = i >> 5, c4 = i & 31;
        float4 val = make_float4(0.f, 0.f, 0.f, 0.f);
        if (row0 + r < NN) val = *reinterpret_cast<const float4*>(&s[(size_t)(row0 + r) * NF + c4 * 4]);
        *reinterpret_cast<float4*>(&sh[r][c4 * 4]) = val;
    }
    __syncthreads();
    {
        const int c = t & 127;
        const int half = t >> 7;
        float hacc[16];
        #pragma unroll
        for (int i = 0; i < 16; ++i) hacc[i] = 0.f;
        for (int k4 = 0; k4 < 32; ++k4) {
            float w0 = W1[(k4 * 4 + 0) * NF + c];
            float w1 = W1[(k4 * 4 + 1) * NF + c];
            float w2 = W1[(k4 * 4 + 2) * NF + c];
            float w3 = W1[(k4 * 4 + 3) * NF + c];
            #pragma unroll
            for (int rr = 0; rr < 16; ++rr) {
                float4 sv = *reinterpret_cast<const float4*>(&sh[half * 16 + rr][k4 * 4]);
                hacc[rr] = fmaf(sv.x, w0, hacc[rr]);
                hacc[rr] = fmaf(sv.y, w1, hacc[rr]);
                hacc[rr] = fmaf(sv.z, w2, hacc[rr]);
                hacc[rr] = fmaf(sv.w, w3, hacc[rr]);
            }
        }
        float b1c = b1[c];
        #pragma unroll
        for (int rr = 0; rr < 16; ++rr) {
            float x = hacc[rr] + b1c;
            float sg = 1.0f / (1.0f + __expf(-x));
            hh[half * 16 + rr][c] = x * sg;
        }
    }
    __syncthreads();
    {
        float pa[32][3];
        #pragma unroll
        for (int r = 0; r < 32; ++r)
            #pragma unroll
            for (int cg = 0; cg < 3; ++cg) pa[r][cg] = 0.f;

        for (int k4 = 0; k4 < 32; ++k4) {
            float w[4][3];
            #pragma unroll
            for (int kk = 0; kk < 4; ++kk)
                #pragma unroll
                for (int cg = 0; cg < 3; ++cg)
                    w[kk][cg] = W2[(size_t)(k4 * 4 + kk) * SIXF + t + 256 * cg];
            #pragma unroll
            for (int r = 0; r < 32; ++r) {
                float4 hv = *reinterpret_cast<const float4*>(&hh[r][k4 * 4]);
                #pragma unroll
                for (int cg = 0; cg < 3; ++cg) {
                    pa[r][cg] = fmaf(hv.x, w[0][cg], pa[r][cg]);
                    pa[r][cg] = fmaf(hv.y, w[1][cg], pa[r][cg]);
                    pa[r][cg] = fmaf(hv.z, w[2][cg], pa[r][cg]);
                    pa[r][cg] = fmaf(hv.w, w[3][cg], pa[r][cg]);
                }
            }
        }
        float b2c[3] = { b2[t], b2[t + 256], b2[t + 512] };
        #pragma unroll
        for (int r = 0; r < 32; ++r) {
            if (row0 + r < NN) {
                #pragma unroll
                for (int cg = 0; cg < 3; ++cg)
                    phiw[(size_t)(row0 + r) * SIXF + t + 256 * cg] = f2bf(pa[r][cg] + b2c[cg]);
            }
        }
    }
}

// ---------------- prep kernels ----------------
__global__ __launch_bounds__(256) void prep_wrb_kernel(
    const float* __restrict__ Wr, const float* __restrict__ br, u16* __restrict__ wrb)
{
    int i = blockIdx.x * 256 + threadIdx.x;
    if (i < 21 * SIXF) wrb[i] = f2bf(i < 20 * SIXF ? Wr[i] : br[i - 20 * SIXF]);
}

__global__ __launch_bounds__(256) void prep_vbf_kernel(
    const float* __restrict__ v, u16* __restrict__ vbf)
{
    int i = blockIdx.x * 256 + threadIdx.x;
    if (i < NN * 384) vbf[i] = f2bf(v[i]);
}

// ---------------- CSR build ----------------
__global__ __launch_bounds__(256) void zero_cnt_kernel(int* __restrict__ cnt) {
    int i = blockIdx.x * 256 + threadIdx.x;
    if (i < NN) cnt[i] = 0;
}

__global__ __launch_bounds__(256) void hist_kernel(const int* __restrict__ eidx, int* __restrict__ cnt) {
    int e = blockIdx.x * 256 + threadIdx.x;
    if (e < NE) atomicAdd(&cnt[eidx[e]], 1);
}

__global__ __launch_bounds__(256) void scan_kernel(const int* __restrict__ cnt, int* __restrict__ offs) {
    __shared__ int part[256];
    const int t = threadIdx.x;
    int lsum = 0;
    if (t < 250) {
        #pragma unroll 4
        for (int k = 0; k < 40; ++k) lsum += cnt[t * 40 + k];
    }
    part[t] = lsum;
    __syncthreads();
    if (t == 0) {
        int run = 0;
        for (int i = 0; i < 250; ++i) { int c = part[i]; part[i] = run; run += c; }
    }
    __syncthreads();
    if (t < 250) {
        int run = part[t];
        for (int k = 0; k < 40; ++k) {
            int idx = t * 40 + k;
            offs[idx] = run;          // exclusive start; scatter mutates to end
            run += cnt[idx];
        }
    }
}

__global__ __launch_bounds__(256) void scatter_kernel(
    const int* __restrict__ eidx, int* __restrict__ offs, int* __restrict__ elist) {
    int e = blockIdx.x * 256 + threadIdx.x;
    if (e < NE) {
        int pos = atomicAdd(&offs[eidx[e]], 1);
        elist[pos] = e;
    }
}

// ---------------- K3: per-node gather ----------------
// RULE-#20 FIX: epilogue e4 loop FULLY UNROLLED so acc[][] is always
// statically indexed -> stays in VGPRs (was demoted to scratch: 1.7 GB spill
// traffic at VGPR_Count=64).
template<bool USE_VBF>
__global__ __launch_bounds__(256, 4) void gather_kernel(
    const float* __restrict__ re1, const float* __restrict__ re2,
    const float* __restrict__ f1, const float* __restrict__ f2,
    const float* __restrict__ u1v, const float* __restrict__ u2v,
    const int* __restrict__ eidx,
    const u16* __restrict__ phiw, const float* __restrict__ v,
    const u16* __restrict__ vbf, const u16* __restrict__ wrb,
    const float* __restrict__ s,
    const int* __restrict__ cnt, const int* __restrict__ offs,
    const int* __restrict__ elist,
    float* __restrict__ out)
{
    __shared__ u16   WrB[K21][SIXF];     // 32,256 B (bf16, row 20 = br)
    __shared__ float smem[2048];         //  8,192 B — staging aliased with redbuf
    float (*rrs)[K21] = (float(*)[K21])smem;            // 672 floats
    float (*euv)[6]   = (float(*)[6])(smem + 672);      // 192 floats
    int*   ejd        = (int*)(smem + 864);             //  32 ints
    float (*redbuf)[512] = (float(*)[512])smem;         // full 2048 (after final sync)

    const int t = threadIdx.x;
    const int node = blockIdx.x;
    const int deg   = cnt[node];
    const int end   = offs[node];        // post-scatter = end boundary
    const int start = end - deg;

    {   // stage precomputed bf16 Wr/br: linear 8064 u32 copy
        const u32* wg = (const u32*)wrb;
        u32* wl = (u32*)&WrB[0][0];
        for (int i = t; i < 8064; i += 256) wl[i] = wg[i];
    }

    const int wave = t >> 6, lane = t & 63;
    float accS[2] = {0.f, 0.f};
    float accV[3][2] = {{0.f,0.f},{0.f,0.f},{0.f,0.f}};

    for (int base = 0; base < deg; base += 32) {
        const int m = min(32, deg - base);
        __syncthreads();   // prior compute done reading rrs/euv/ejd (covers WrB on iter 0)
        for (int i = t; i < m * K21; i += 256) {
            int el = i / K21, r = i - el * K21;
            int e = elist[start + base + el];
            float a;
            if (r < 20) a = f1[e] * re1[(size_t)e * 20 + r] + f2[e] * re2[(size_t)e * 20 + r];
            else        a = f1[e] + f2[e];
            rrs[el][r] = a;
        }
        if (t < m) {
            int e = elist[start + base + t];
            ejd[t] = eidx[NE + e];
            #pragma unroll
            for (int d = 0; d < 3; ++d) {
                euv[t][d]     = u1v[(size_t)e * 3 + d];
                euv[t][3 + d] = u2v[(size_t)e * 3 + d];
            }
        }
        __syncthreads();

        #pragma unroll 1
        for (int half = 0; half < 2; ++half) {
            const int eg = wave * 8 + half * 4;
            if (eg >= m) continue;
            float acc[4][12];
            #pragma unroll
            for (int ea = 0; ea < 4; ++ea)
                #pragma unroll
                for (int cb = 0; cb < 12; ++cb) acc[ea][cb] = 0.f;

            for (int r = 0; r < K21; ++r) {
                float wv[12];
                #pragma unroll
                for (int cc = 0; cc < 6; ++cc) {
                    u32 pk = *reinterpret_cast<const u32*>(&WrB[r][cc * 128 + 2 * lane]);
                    wv[2 * cc]     = bf2f_lo(pk);
                    wv[2 * cc + 1] = bf2f_hi(pk);
                }
                #pragma unroll
                for (int e4 = 0; e4 < 4; ++e4) {
                    float a = rrs[eg + e4][r];
                    #pragma unroll
                    for (int c = 0; c < 12; ++c) acc[e4][c] = fmaf(a, wv[c], acc[e4][c]);
                }
            }

            #pragma unroll   // FULL unroll: static acc indexing (rule #20)
            for (int e4 = 0; e4 < 4; ++e4) {
                const int el = eg + e4;
                if (el < m) {
                    const int nj = ejd[el];
                    const float u1x = euv[el][0], u1y = euv[el][1], u1z = euv[el][2];
                    const float u2x = euv[el][3], u2y = euv[el][4], u2z = euv[el][5];
                    const u16* ph = phiw + (size_t)nj * SIXF + 2 * lane;
                    float px[12];
                    #pragma unroll
                    for (int cc = 0; cc < 6; ++cc) {
                        u32 pk = *reinterpret_cast<const u32*>(ph + cc * 128);
                        px[2 * cc]     = bf2f_lo(pk);
                        px[2 * cc + 1] = bf2f_hi(pk);
                    }
                    float2 va, vb, vc;
                    if (USE_VBF) {
                        const u16* vj = vbf + (size_t)nj * 384 + 2 * lane;
                        u32 p0 = *reinterpret_cast<const u32*>(vj);
                        u32 p1 = *reinterpret_cast<const u32*>(vj + 128);
                        u32 p2 = *reinterpret_cast<const u32*>(vj + 256);
                        va = make_float2(bf2f_lo(p0), bf2f_hi(p0));
                        vb = make_float2(bf2f_lo(p1), bf2f_hi(p1));
                        vc = make_float2(bf2f_lo(p2), bf2f_hi(p2));
                    } else {
                        const float* vj = v + (size_t)nj * 384 + 2 * lane;
                        va = *reinterpret_cast<const float2*>(vj);
                        vb = *reinterpret_cast<const float2*>(vj + 128);
                        vc = *reinterpret_cast<const float2*>(vj + 256);
                    }
                    #pragma unroll
                    for (int ff = 0; ff < 2; ++ff) {
                        float xs   = acc[e4][0 + ff]  * px[0 + ff];
                        float xvv  = acc[e4][2 + ff]  * px[2 + ff];
                        float xvs1 = acc[e4][4 + ff]  * px[4 + ff];
                        float xvs2 = acc[e4][6 + ff]  * px[6 + ff];
                        float xvc1 = acc[e4][8 + ff]  * px[8 + ff];
                        float xvc2 = acc[e4][10 + ff] * px[10 + ff];
                        float a0 = ff ? va.y : va.x;
                        float a1 = ff ? vb.y : vb.x;
                        float a2 = ff ? vc.y : vc.x;
                        float c1x = a1 * u1z - a2 * u1y;
                        float c1y = a2 * u1x - a0 * u1z;
                        float c1z = a0 * u1y - a1 * u1x;
                        float c2x = a1 * u2z - a2 * u2y;
                        float c2y = a2 * u2x - a0 * u2z;
                        float c2z = a0 * u2y - a1 * u2x;
                        accS[ff] += xs;
                        accV[0][ff] += a0 * xvv + xvs1 * u1x + xvs2 * u2x + xvc1 * c1x + xvc2 * c2x;
                        accV[1][ff] += a1 * xvv + xvs1 * u1y + xvs2 * u2y + xvc1 * c1y + xvc2 * c2y;
                        accV[2][ff] += a2 * xvv + xvs1 * u1z + xvs2 * u2z + xvc1 * c1z + xvc2 * c2z;
                    }
                }
            }
        }
    }

    // cross-wave reduction + single write (s/v base folded in)
    __syncthreads();
    #pragma unroll
    for (int ff = 0; ff < 2; ++ff) {
        redbuf[wave][2 * lane + ff] = accS[ff];
        #pragma unroll
        for (int d = 0; d < 3; ++d)
            redbuf[wave][128 + d * 128 + 2 * lane + ff] = accV[d][ff];
    }
    __syncthreads();
    for (int k = t; k < 512; k += 256) {
        float sum = redbuf[0][k] + redbuf[1][k] + redbuf[2][k] + redbuf[3][k];
        if (k < NF) {
            out[(size_t)node * NF + k] = s[(size_t)node * NF + k] + sum;
        } else {
            int kv = k - NF;   // d*128 + f
            out[(size_t)NN * NF + (size_t)node * 384 + kv] = v[(size_t)node * 384 + kv] + sum;
        }
    }
}

// ---------------- K3-fallback: atomic edge kernel ----------------
__global__ __launch_bounds__(256) void edge_kernel(
    const float* __restrict__ re1, const float* __restrict__ re2,
    const float* __restrict__ f1, const float* __restrict__ f2,
    const float* __restrict__ u1v, const float* __restrict__ u2v,
    const int* __restrict__ eidx,
    const u16* __restrict__ phiw, const float* __restrict__ v,
    const float* __restrict__ Wr, const float* __restrict__ br,
    float* __restrict__ out)
{
    __shared__ u16   WrB[K21][SIXF];
    __shared__ float rrs[32][K21];
    __shared__ float euv[32][6];
    __shared__ int   eid[32][2];
    const int t = threadIdx.x;
    const int e0 = blockIdx.x * 32;

    for (int i = t; i < 20 * SIXF; i += 256) WrB[0][i] = f2bf(Wr[i]);
    for (int c = t; c < SIXF; c += 256)      WrB[20][c] = f2bf(br[c]);
    for (int i = t; i < 32 * K21; i += 256) {
        int el = i / K21, r = i - el * K21;
        int e = e0 + el;
        float a;
        if (r < 20) a = f1[e] * re1[(size_t)e * 20 + r] + f2[e] * re2[(size_t)e * 20 + r];
        else        a = f1[e] + f2[e];
        rrs[el][r] = a;
    }
    if (t < 32) {
        int e = e0 + t;
        eid[t][0] = eidx[e];
        eid[t][1] = eidx[NE + e];
        #pragma unroll
        for (int d = 0; d < 3; ++d) {
            euv[t][d]     = u1v[(size_t)e * 3 + d];
            euv[t][3 + d] = u2v[(size_t)e * 3 + d];
        }
    }
    __syncthreads();

    const int wave = t >> 6, lane = t & 63;
    #pragma unroll 1
    for (int half = 0; half < 2; ++half) {
        const int eg = wave * 8 + half * 4;
        float acc[4][12];
        #pragma unroll
        for (int ea = 0; ea < 4; ++ea)
            #pragma unroll
            for (int cb = 0; cb < 12; ++cb) acc[ea][cb] = 0.f;

        for (int r = 0; r < K21; ++r) {
            float wv[12];
            #pragma unroll
            for (int cc = 0; cc < 6; ++cc) {
                u32 pk = *reinterpret_cast<const u32*>(&WrB[r][cc * 128 + 2 * lane]);
                wv[2 * cc]     = bf2f_lo(pk);
                wv[2 * cc + 1] = bf2f_hi(pk);
            }
            #pragma unroll
            for (int e4 = 0; e4 < 4; ++e4) {
                float a = rrs[eg + e4][r];
                #pragma unroll
                for (int c = 0; c < 12; ++c) acc[e4][c] = fmaf(a, wv[c], acc[e4][c]);
            }
        }

        #pragma unroll   // FULL unroll (rule #20)
        for (int e4 = 0; e4 < 4; ++e4) {
            const int el = eg + e4;
            const int ni = eid[el][0], nj = eid[el][1];
            const float u1x = euv[el][0], u1y = euv[el][1], u1z = euv[el][2];
            const float u2x = euv[el][3], u2y = euv[el][4], u2z = euv[el][5];
            const u16* ph = phiw + (size_t)nj * SIXF + 2 * lane;
            float px[12];
            #pragma unroll
            for (int cc = 0; cc < 6; ++cc) {
                u32 pk = *reinterpret_cast<const u32*>(ph + cc * 128);
                px[2 * cc]     = bf2f_lo(pk);
                px[2 * cc + 1] = bf2f_hi(pk);
            }
            const float* vj = v + (size_t)nj * 384 + 2 * lane;
            float2 va = *reinterpret_cast<const float2*>(vj);
            float2 vb = *reinterpret_cast<const float2*>(vj + 128);
            float2 vc = *reinterpret_cast<const float2*>(vj + 256);
            float* po = out + (size_t)ni * NF + 2 * lane;
            float* pv = out + (size_t)NN * NF + (size_t)ni * 384 + 2 * lane;
            #pragma unroll
            for (int ff = 0; ff < 2; ++ff) {
                float xs   = acc[e4][0 + ff]  * px[0 + ff];
                float xvv  = acc[e4][2 + ff]  * px[2 + ff];
                float xvs1 = acc[e4][4 + ff]  * px[4 + ff];
                float xvs2 = acc[e4][6 + ff]  * px[6 + ff];
                float xvc1 = acc[e4][8 + ff]  * px[8 + ff];
                float xvc2 = acc[e4][10 + ff] * px[10 + ff];
                float a0 = ff ? va.y : va.x;
                float a1 = ff ? vb.y : vb.x;
                float a2 = ff ? vc.y : vc.x;
                float c1x = a1 * u1z - a2 * u1y;
                float c1y = a2 * u1x - a0 * u1z;
                float c1z = a0 * u1y - a1 * u1x;
                float c2x = a1 * u2z - a2 * u2y;
                float c2y = a2 * u2x - a0 * u2z;
                float c2z = a0 * u2y - a1 * u2x;
                float xv0 = a0 * xvv + xvs1 * u1x + xvs2 * u2x + xvc1 * c1x + xvc2 * c2x;
                float xv1 = a1 * xvv + xvs1 * u1y + xvs2 * u2y + xvc1 * c1y + xvc2 * c2y;
                float xv2 = a2 * xvv + xvs1 * u1z + xvs2 * u2z + xvc1 * c1z + xvc2 * c2z;
                unsafeAtomicAdd(po + ff, xs);
                unsafeAtomicAdd(pv + ff, xv0);
                unsafeAtomicAdd(pv + 128 + ff, xv1);
                unsafeAtomicAdd(pv + 256 + ff, xv2);
            }
        }
    }
}

extern "C" void kernel_launch(void* const* d_in, const int* in_sizes, int n_in,
                              void* d_out, int out_size, void* d_ws, size_t ws_size,
                              hipStream_t stream) {
    const float* s   = (const float*)d_in[0];
    const float* v   = (const float*)d_in[1];
    const float* re1 = (const float*)d_in[2];
    const float* re2 = (const float*)d_in[3];
    const float* f1  = (const float*)d_in[4];
    const float* f2  = (const float*)d_in[5];
    const float* u1  = (const float*)d_in[6];
    const float* u2  = (const float*)d_in[7];
    const int*   ei  = (const int*)d_in[8];
    const float* W1  = (const float*)d_in[9];
    const float* b1  = (const float*)d_in[10];
    const float* W2  = (const float*)d_in[11];
    const float* b2  = (const float*)d_in[12];
    const float* Wr  = (const float*)d_in[13];
    const float* br  = (const float*)d_in[14];
    float* out = (float*)d_out;

    const size_t PHI_B  = (size_t)NN * SIXF * 2;   // 15,360,000
    const size_t VBF_B  = (size_t)NN * 384 * 2;    //  7,680,000
    const size_t CNT_B  = (size_t)NN * 4;          //     40,000
    const size_t EL_B   = (size_t)NE * 4;          //  1,280,000
    const size_t WRB_B  = (size_t)21 * SIXF * 2;   //     32,256

    const size_t need_full = PHI_B + VBF_B + 2 * CNT_B + EL_B + WRB_B;  // 24.43 MB
    const size_t need_csr  = PHI_B + 2 * CNT_B + EL_B + WRB_B;          // 16.75 MB

    u16* phiw = (u16*)d_ws;
    phi_kernel<<<dim3((NN + 31) / 32), dim3(256), 0, stream>>>(s, W1, b1, W2, b2, phiw);

    if (ws_size >= need_full) {
        u16* vbf   = (u16*)((char*)d_ws + PHI_B);
        int* cnt   = (int*)((char*)d_ws + PHI_B + VBF_B);
        int* offs  = cnt + NN;
        int* elist = offs + NN;
        u16* wrb   = (u16*)((char*)elist + EL_B);

        prep_wrb_kernel<<<dim3((21 * SIXF + 255) / 256), dim3(256), 0, stream>>>(Wr, br, wrb);
        prep_vbf_kernel<<<dim3((NN * 384 + 255) / 256), dim3(256), 0, stream>>>(v, vbf);
        zero_cnt_kernel<<<dim3((NN + 255) / 256), dim3(256), 0, stream>>>(cnt);
        hist_kernel<<<dim3((NE + 255) / 256), dim3(256), 0, stream>>>(ei, cnt);
        scan_kernel<<<dim3(1), dim3(256), 0, stream>>>(cnt, offs);
        scatter_kernel<<<dim3((NE + 255) / 256), dim3(256), 0, stream>>>(ei, offs, elist);
        gather_kernel<true><<<dim3(NN), dim3(256), 0, stream>>>(
            re1, re2, f1, f2, u1, u2, ei, phiw, v, vbf, wrb, s, cnt, offs, elist, out);
    } else if (ws_size >= need_csr) {
        int* cnt   = (int*)((char*)d_ws + PHI_B);
        int* offs  = cnt + NN;
        int* elist = offs + NN;
        u16* wrb   = (u16*)((char*)elist + EL_B);

        prep_wrb_kernel<<<dim3((21 * SIXF + 255) / 256), dim3(256), 0, stream>>>(Wr, br, wrb);
        zero_cnt_kernel<<<dim3((NN + 255) / 256), dim3(256), 0, stream>>>(cnt);
        hist_kernel<<<dim3((NE + 255) / 256), dim3(256), 0, stream>>>(ei, cnt);
        scan_kernel<<<dim3(1), dim3(256), 0, stream>>>(cnt, offs);
        scatter_kernel<<<dim3((NE + 255) / 256), dim3(256), 0, stream>>>(ei, offs, elist);
        gather_kernel<false><<<dim3(NN), dim3(256), 0, stream>>>(
            re1, re2, f1, f2, u1, u2, ei, phiw, v, (const u16*)nullptr, wrb, s, cnt, offs, elist, out);
    } else {
        init_out_kernel<<<dim3((NN * NF + NN * 3 * NF) / 4 / 256), dim3(256), 0, stream>>>(
            (const float4*)s, (const float4*)v, (float4*)out);
        edge_kernel<<<dim3(NE / 32), dim3(256), 0, stream>>>(
            re1, re2, f1, f2, u1, u2, ei, phiw, v, Wr, br, out);
    }
}